// Round 3
// baseline (385.235 us; speedup 1.0000x reference)
//
#include <hip/hip_runtime.h>
#include <hip/hip_bf16.h>

typedef __attribute__((ext_vector_type(8))) short short8;
typedef __attribute__((ext_vector_type(4))) float f32x4;

#define DEVI static __device__ __forceinline__

constexpr int Bb = 2, Ss = 2048, Hh = 32, KVc = 4, Dc = 128;
constexpr float EPSc = 1e-6f;
constexpr float SCALEc = 0.08838834764831845f; // 1/sqrt(128)

DEVI float bf2f(short s) {
  unsigned u = ((unsigned)(unsigned short)s) << 16;
  float f; __builtin_memcpy(&f, &u, 4); return f;
}
DEVI short f2bf(float f) {
  __hip_bfloat16 h = __float2bfloat16(f);
  unsigned short u; __builtin_memcpy(&u, &h, 2); return (short)u;
}

// async global->LDS, 16B per lane. LDS dest must be linear (base + lane*16).
#define GLDS(gsrc, ldst) __builtin_amdgcn_global_load_lds( \
    (const __attribute__((address_space(1))) void*)(gsrc), \
    (__attribute__((address_space(3))) void*)(ldst), 16, 0, 0)

// ---------------- f32 -> bf16 convert ----------------
__global__ void cvt_kernel(const float* __restrict__ in, short* __restrict__ out, int n4) {
  int i = blockIdx.x * blockDim.x + threadIdx.x;
  if (i < n4) {
    float4 v = ((const float4*)in)[i];
    short4 o;
    o.x = f2bf(v.x); o.y = f2bf(v.y); o.z = f2bf(v.z); o.w = f2bf(v.w);
    ((short4*)out)[i] = o;
  }
}

// ---------------- GEMM: C[m][n] = sum_k A[m][k] * B[n][k]  (both row-major, bf16) ----
// 1D grid, XCD-aware decode: blocks with the same bid%8 (same XCD) own a
// contiguous range of nt (B-panels) so each panel is fetched into one L2.
// MODE 0: fused QKV, grid 1280 = 8 xcd * (5 nt * 32 mt)
// MODE 1: out-proj, grid 512 = 8 xcd * (2 nt * 32 mt), f32 out
template<int MODE>
__launch_bounds__(256, 2)
__global__ void gemm_bt(const short* __restrict__ A,
                        const short* __restrict__ B0,
                        const short* __restrict__ B1,
                        const short* __restrict__ B2,
                        short* __restrict__ oq,
                        short* __restrict__ ok,
                        short* __restrict__ ov,
                        float* __restrict__ of,
                        int K)
{
  __shared__ short lA[128 * 32];
  __shared__ short lB[128 * 32];
  const int tid = threadIdx.x;
  const int lane = tid & 63;
  const int wvi = tid >> 6;
  const int l15 = lane & 15, g = lane >> 4;
  const int bid = blockIdx.x;
  const int xcd = bid & 7, idx = bid >> 3;
  const int nt = (MODE == 0) ? (xcd * 5 + (idx >> 5)) : (xcd * 2 + (idx >> 5));
  const int m0 = (idx & 31) * 128;
  const short* Bp; int n0, region;
  if (MODE == 0) {
    if (nt < 32)      { Bp = B0; n0 = nt * 128;        region = 0; }
    else if (nt < 36) { Bp = B1; n0 = (nt - 32) * 128; region = 1; }
    else              { Bp = B2; n0 = (nt - 36) * 128; region = 2; }
  } else { Bp = B0; n0 = nt * 128; region = 3; }

  const int wm = (wvi >> 1) * 64, wn = (wvi & 1) * 64;
  const int srow = tid >> 2, schunk = tid & 3;

  f32x4 acc[4][4] = {};

  for (int k0 = 0; k0 < K; k0 += 32) {
    __syncthreads();
#pragma unroll
    for (int c = 0; c < 2; ++c) {
      int row = c * 64 + srow;
      int gc = schunk ^ ((row >> 1) & 3);   // inverse-swizzled global source
      GLDS(A  + (size_t)(m0 + row) * K + k0 + gc * 8, lA + (c * 256 + tid) * 8);
      GLDS(Bp + (size_t)(n0 + row) * K + k0 + gc * 8, lB + (c * 256 + tid) * 8);
    }
    __syncthreads();
    short8 afr[4], bfr[4];
#pragma unroll
    for (int i = 0; i < 4; ++i) {
      int ra = wm + i * 16 + l15;
      afr[i] = *(const short8*)(lA + ra * 32 + ((g ^ ((ra >> 1) & 3)) * 8));
      int rb = wn + i * 16 + l15;
      bfr[i] = *(const short8*)(lB + rb * 32 + ((g ^ ((rb >> 1) & 3)) * 8));
    }
#pragma unroll
    for (int mi = 0; mi < 4; ++mi)
#pragma unroll
      for (int ni = 0; ni < 4; ++ni)
        acc[mi][ni] = __builtin_amdgcn_mfma_f32_16x16x32_bf16(afr[mi], bfr[ni], acc[mi][ni], 0, 0, 0);
  }

#pragma unroll
  for (int mi = 0; mi < 4; ++mi)
#pragma unroll
    for (int ni = 0; ni < 4; ++ni)
#pragma unroll
      for (int r = 0; r < 4; ++r) {
        int m = m0 + wm + mi * 16 + g * 4 + r;
        int n = n0 + wn + ni * 16 + l15;
        float v = acc[mi][ni][r];
        if (MODE == 1) {
          of[(size_t)m * 2048 + n] = v;
        } else if (region == 0) {
          oq[(size_t)m * 4096 + n] = f2bf(v);
        } else {
          int b = m >> 11, s = m & 2047, kvi = n >> 7, d = n & 127;
          if (region == 1)
            ok[(((size_t)b * KVc + kvi) * Ss + s) * 128 + d] = f2bf(v);
          else
            ov[(((size_t)b * KVc + kvi) * 128 + d) * Ss + s] = f2bf(v);
        }
      }
}

// ---------------- RMSNorm + RoPE (one wave per (token, head) row of 128) ----------
// ISQ also folds the attention softmax scale (1/sqrt(D)) into q.
template<bool ISQ>
__global__ void rmsnorm_rope(short* __restrict__ buf, const float* __restrict__ w,
                             const float* __restrict__ cosb, const float* __restrict__ sinb)
{
  const int lane = threadIdx.x & 63;
  const int wvi = threadIdx.x >> 6;
  const int i = blockIdx.x * 4 + wvi;
  short* row;
  int b, s;
  if (ISQ) {
    int m = i >> 5, h = i & 31;
    b = m >> 11; s = m & 2047;
    row = buf + (size_t)m * 4096 + h * 128;
  } else {
    s = i & 2047; int bkv = i >> 11; b = bkv >> 2;
    row = buf + (size_t)i * 128;
  }
  float x1 = bf2f(row[lane]), x2 = bf2f(row[lane + 64]);
  float ss = x1 * x1 + x2 * x2;
#pragma unroll
  for (int o = 32; o; o >>= 1) ss += __shfl_xor(ss, o);
  float inv = rsqrtf(ss * (1.0f / 128.0f) + EPSc);
  const float* cp = cosb + ((size_t)b * Ss + s) * Dc;
  const float* sp = sinb + ((size_t)b * Ss + s) * Dc;
  float n1 = x1 * inv * w[lane], n2 = x2 * inv * w[lane + 64];
  float o1 = n1 * cp[lane]      - n2 * sp[lane];
  float o2 = n2 * cp[lane + 64] + n1 * sp[lane + 64];
  if (ISQ) { o1 *= SCALEc; o2 *= SCALEc; }
  row[lane]      = f2bf(o1);
  row[lane + 64] = f2bf(o2);
}

// ---------------- Flash attention (GQA, causal) ----------------
// 4 waves x 32 q-rows = 128-row q tile per block. Causal pairing: block pi
// handles q-tiles (pi, 15-pi) sequentially -> every block does 34 k-iters.
// KVBLK=64, double-buffered LDS, counted vmcnt (never drain-0 in loop).
// Swapped QK^T: mfma(A=K, B=Q) -> lane holds S^T[k_local=4g+r][q_local=l15].
// Q comes pre-scaled by 1/sqrt(D). Defer-max (THR=8) skips O-rescale.
__launch_bounds__(256, 2)
__global__ void attn_fwd(const short* __restrict__ qb,
                         const short* __restrict__ kbuf,
                         const short* __restrict__ vtbuf,
                         short* __restrict__ ob)
{
  __shared__ short lK[2][64 * 128];   // 32 KiB
  __shared__ short lV[2][128 * 64];   // 32 KiB
  __shared__ short lP[4][32 * 32];    //  8 KiB
  const int tid = threadIdx.x, lane = tid & 63, wvi = tid >> 6;
  const int l15 = lane & 15, g = lane >> 4;
  const int pi = blockIdx.x, h = blockIdx.y, b = blockIdx.z;
  const int kv = h >> 3;              // G = 8
  const short* kp = kbuf  + ((size_t)b * KVc + kv) * Ss * 128;
  const short* vp = vtbuf + ((size_t)b * KVc + kv) * 128 * Ss;
  const int krow = tid >> 4, kch = tid & 15;   // K tile [64][128]: 16 chunks/row
  const int vrow = tid >> 3, vch = tid & 7;    // V^T tile [128][64]: 8 chunks/row

  for (int which = 0; which < 2; ++which) {
    const int qt = which ? (15 - pi) : pi;
    const int qwb = qt * 128 + wvi * 32;
    const int nkt = 2 * qt + 2;       // 64-key tiles needed

    short8 qf[2][4];
#pragma unroll
    for (int qs = 0; qs < 2; ++qs)
#pragma unroll
      for (int dc = 0; dc < 4; ++dc)
        qf[qs][dc] = *(const short8*)(qb + (size_t)(b * Ss + qwb + qs * 16 + l15) * 4096
                                         + h * 128 + dc * 32 + g * 8);

    f32x4 oacc[2][8] = {};
    float mrun[2] = { -__builtin_inff(), -__builtin_inff() };
    float lrun[2] = { 0.f, 0.f };

    auto STAGE = [&](int kt, int bufi) {   // 8 GLDS per lane
      const int kb0 = kt * 64;
#pragma unroll
      for (int c = 0; c < 4; ++c) {        // K [64][128]
        int r = c * 16 + krow;
        int gc = kch ^ (r & 7);
        GLDS(kp + (size_t)(kb0 + r) * 128 + gc * 8, &lK[bufi][(c * 256 + tid) * 8]);
      }
#pragma unroll
      for (int c = 0; c < 4; ++c) {        // V^T [128][64]
        int r = c * 32 + vrow;
        int gc = vch ^ (r & 7);
        GLDS(vp + (size_t)r * Ss + kb0 + gc * 8, &lV[bufi][(c * 256 + tid) * 8]);
      }
    };

    STAGE(0, 0);
    STAGE(1, 1);                        // nkt >= 2 always

    for (int kt = 0; kt < nkt; ++kt) {
      const int cb = kt & 1;
      if (kt + 1 < nkt) asm volatile("s_waitcnt vmcnt(8)" ::: "memory");
      else              asm volatile("s_waitcnt vmcnt(0)" ::: "memory");
      __builtin_amdgcn_s_barrier();
      asm volatile("" ::: "memory");

#pragma unroll
      for (int half = 0; half < 2; ++half) {
        const int kb0 = kt * 64 + half * 32;
        if (kb0 <= qwb + 31) {
          short8 kf[2][4];
#pragma unroll
          for (int ks = 0; ks < 2; ++ks)
#pragma unroll
            for (int dc = 0; dc < 4; ++dc) {
              int row = half * 32 + ks * 16 + l15;
              kf[ks][dc] = *(const short8*)(&lK[cb][0] + row * 128 + (((dc * 4 + g) ^ (row & 7)) * 8));
            }
          f32x4 st[2][2] = {};
          __builtin_amdgcn_s_setprio(1);
#pragma unroll
          for (int qs = 0; qs < 2; ++qs)
#pragma unroll
            for (int ks = 0; ks < 2; ++ks)
#pragma unroll
              for (int dc = 0; dc < 4; ++dc)
                st[qs][ks] = __builtin_amdgcn_mfma_f32_16x16x32_bf16(kf[ks][dc], qf[qs][dc], st[qs][ks], 0, 0, 0);
          __builtin_amdgcn_s_setprio(0);

          const bool need_mask = (kb0 + 31 > qwb);
#pragma unroll
          for (int qs = 0; qs < 2; ++qs) {
            const int qg = qwb + qs * 16 + l15;
            float p[8];
            float tmax = -__builtin_inff();
#pragma unroll
            for (int ks = 0; ks < 2; ++ks)
#pragma unroll
              for (int r = 0; r < 4; ++r) {
                float v = st[qs][ks][r];
                if (need_mask && (kb0 + ks * 16 + g * 4 + r > qg)) v = -__builtin_inff();
                p[ks * 4 + r] = v;
                tmax = fmaxf(tmax, v);
              }
            tmax = fmaxf(tmax, __shfl_xor(tmax, 16));
            tmax = fmaxf(tmax, __shfl_xor(tmax, 32));
            // defer-max: only rescale O when the running max grows by > 8
            float m_use = mrun[qs];
            if (__any(tmax > m_use + 8.0f)) {
              float mnew = fmaxf(m_use, tmax);
              float scl = __expf(m_use - mnew);   // -inf first tile -> 0
              lrun[qs] *= scl;
              mrun[qs] = mnew;
#pragma unroll
              for (int r = 0; r < 4; ++r) {
                float sc = __shfl(scl, g * 4 + r);
#pragma unroll
                for (int dt = 0; dt < 8; ++dt)
                  oacc[qs][dt][r] *= sc;
              }
              m_use = mnew;
            }
            float rsum = 0.f;
#pragma unroll
            for (int j = 0; j < 8; ++j) { p[j] = __expf(p[j] - m_use); rsum += p[j]; }
            rsum += __shfl_xor(rsum, 16);
            rsum += __shfl_xor(rsum, 32);
            lrun[qs] += rsum;
            {
              int row = qs * 16 + l15;
              int sw = (row >> 1) & 3;
              short* pr = lP[wvi] + row * 32;
#pragma unroll
              for (int ks = 0; ks < 2; ++ks) {
                int idx = (((2 * ks + (g >> 1)) ^ sw) * 8) + (g & 1) * 4; // k = 16ks+4g+r
                short4 pw;
                pw.x = f2bf(p[ks * 4 + 0]);
                pw.y = f2bf(p[ks * 4 + 1]);
                pw.z = f2bf(p[ks * 4 + 2]);
                pw.w = f2bf(p[ks * 4 + 3]);
                *(short4*)(pr + idx) = pw;
              }
            }
          }
          asm volatile("" ::: "memory");   // order lP writes before lP reads (in-wave)
          short8 vf[8];
#pragma unroll
          for (int dt = 0; dt < 8; ++dt) {
            int row = dt * 16 + l15;
            vf[dt] = *(const short8*)(&lV[cb][0] + row * 64 + (((half * 4 + g) ^ (row & 7)) * 8));
          }
          __builtin_amdgcn_s_setprio(1);
#pragma unroll
          for (int qs = 0; qs < 2; ++qs) {
            int row = qs * 16 + l15;
            short8 pf = *(const short8*)(lP[wvi] + row * 32 + ((g ^ ((row >> 1) & 3)) * 8));
#pragma unroll
            for (int dt = 0; dt < 8; ++dt)
              oacc[qs][dt] = __builtin_amdgcn_mfma_f32_16x16x32_bf16(pf, vf[dt], oacc[qs][dt], 0, 0, 0);
          }
          __builtin_amdgcn_s_setprio(0);
          asm volatile("" ::: "memory");
        }
      }

      asm volatile("" ::: "memory");
      __builtin_amdgcn_s_barrier();      // everyone done reading buf[cb]
      if (kt + 2 < nkt) STAGE(kt + 2, cb);
    }

#pragma unroll
    for (int qs = 0; qs < 2; ++qs)
#pragma unroll
      for (int r = 0; r < 4; ++r) {
        float inv = 1.0f / __shfl(lrun[qs], g * 4 + r);
        int qrow = qwb + qs * 16 + g * 4 + r;
        short* op = ob + (size_t)(b * Ss + qrow) * 4096 + h * 128;
#pragma unroll
        for (int dt = 0; dt < 8; ++dt)
          op[dt * 16 + l15] = f2bf(oacc[qs][dt][r] * inv);
      }
  }
}

// ---------------- host ----------------
extern "C" void kernel_launch(void* const* d_in, const int* in_sizes, int n_in,
                              void* d_out, int out_size, void* d_ws, size_t ws_size,
                              hipStream_t stream) {
  const float* x    = (const float*)d_in[0];
  const float* cosb = (const float*)d_in[1];
  const float* sinb = (const float*)d_in[2];
  const float* wq   = (const float*)d_in[3];
  const float* wk   = (const float*)d_in[4];
  const float* wv   = (const float*)d_in[5];
  const float* wo   = (const float*)d_in[6];
  const float* qw   = (const float*)d_in[7];
  const float* kw   = (const float*)d_in[8];

  size_t off = 0;
  auto alloc = [&](size_t bytes) {
    char* p = (char*)d_ws + off;
    off += (bytes + 255) & ~(size_t)255;
    return p;
  };
  short* x_bf  = (short*)alloc((size_t)8388608 * 2);
  short* wq_bf = (short*)alloc((size_t)8388608 * 2);
  short* wk_bf = (short*)alloc((size_t)1048576 * 2);
  short* wv_bf = (short*)alloc((size_t)1048576 * 2);
  short* wo_bf = (short*)alloc((size_t)8388608 * 2);
  short* q_bf  = (short*)alloc((size_t)16777216 * 2);
  short* k_bf  = (short*)alloc((size_t)2097152 * 2);
  short* v_bf  = (short*)alloc((size_t)2097152 * 2);
  short* ao_bf = (short*)alloc((size_t)16777216 * 2);

  auto cv = [&](const float* s, short* d, int n) {
    int n4 = n / 4;
    cvt_kernel<<<(n4 + 255) / 256, 256, 0, stream>>>(s, d, n4);
  };
  cv(x,  x_bf,  8388608);
  cv(wq, wq_bf, 8388608);
  cv(wk, wk_bf, 1048576);
  cv(wv, wv_bf, 1048576);
  cv(wo, wo_bf, 8388608);

  gemm_bt<0><<<1280, 256, 0, stream>>>(x_bf, wq_bf, wk_bf, wv_bf,
                                       q_bf, k_bf, v_bf, nullptr, 2048);
  rmsnorm_rope<true><<<32768, 256, 0, stream>>>(q_bf, qw, cosb, sinb);
  rmsnorm_rope<false><<<4096, 256, 0, stream>>>(k_bf, kw, cosb, sinb);
  attn_fwd<<<dim3(8, 32, 2), 256, 0, stream>>>(q_bf, k_bf, v_bf, ao_bf);
  gemm_bt<1><<<512, 256, 0, stream>>>(ao_bf, wo_bf, nullptr, nullptr,
                                      nullptr, nullptr, nullptr, (float*)d_out, 4096);
}

// Round 4
// 354.979 us; speedup vs baseline: 1.0852x; 1.0852x over previous
//
#include <hip/hip_runtime.h>
#include <hip/hip_bf16.h>

typedef __attribute__((ext_vector_type(8))) short short8;
typedef __attribute__((ext_vector_type(4))) float f32x4;

#define DEVI static __device__ __forceinline__

constexpr int Bb = 2, Ss = 2048, Hh = 32, KVc = 4, Dc = 128;
constexpr float EPSc = 1e-6f;
constexpr float SCALEc = 0.08838834764831845f; // 1/sqrt(128)

DEVI float bf2f(short s) {
  unsigned u = ((unsigned)(unsigned short)s) << 16;
  float f; __builtin_memcpy(&f, &u, 4); return f;
}
DEVI short f2bf(float f) {
  __hip_bfloat16 h = __float2bfloat16(f);
  unsigned short u; __builtin_memcpy(&u, &h, 2); return (short)u;
}

// async global->LDS, 16B per lane. LDS dest must be linear (base + lane*16).
#define GLDS(gsrc, ldst) __builtin_amdgcn_global_load_lds( \
    (const __attribute__((address_space(1))) void*)(gsrc), \
    (__attribute__((address_space(3))) void*)(ldst), 16, 0, 0)

// ---------------- fused f32 -> bf16 convert (5 segments, 1 launch) ----------------
struct Cvt5 { const float* src[5]; short* dst[5]; };
__global__ void cvt_all(Cvt5 a) {
  // float4 counts: x 2097152, wq 2097152, wk 262144, wv 262144, wo 2097152
  constexpr int CUM[6] = {0, 2097152, 4194304, 4456448, 4718592, 6815744};
  const int stride = gridDim.x * blockDim.x;
  for (int i = blockIdx.x * blockDim.x + threadIdx.x; i < 6815744; i += stride) {
    int s = 0;
#pragma unroll
    for (int t = 1; t < 5; ++t) if (i >= CUM[t]) s = t;
    int j = i - CUM[s];
    float4 v = ((const float4*)a.src[s])[j];
    short4 o;
    o.x = f2bf(v.x); o.y = f2bf(v.y); o.z = f2bf(v.z); o.w = f2bf(v.w);
    ((short4*)a.dst[s])[j] = o;
  }
}

// ---------------- GEMM: C[m][n] = sum_k A[m][k] * B[n][k]  (both row-major, bf16) ----
// Grid dim3(32, nt): bid%8 == m_tile%8 -> A-tiles are XCD-stationary (2MB/XCD in L2),
// B panels stream. (Round-3 remap regressed this; reverted.)
// Wave tile 32m x 128n: each wave owns full head-dim per row -> RMSNorm+RoPE
// fuse entirely in-lane (partner col n^64 is ni^4 in the same lane).
// MODE 0: fused QKV. q: norm+rope+scale; k: norm+rope -> [b][kv][s][d]; v -> [b][kv][d][s].
// MODE 1: out-proj, f32 row-major out (N=2048).
template<int MODE>
__launch_bounds__(256, 2)
__global__ void gemm_bt(const short* __restrict__ A,
                        const short* __restrict__ B0,
                        const short* __restrict__ B1,
                        const short* __restrict__ B2,
                        short* __restrict__ oq,
                        short* __restrict__ ok,
                        short* __restrict__ ov,
                        float* __restrict__ of,
                        const float* __restrict__ cosb,
                        const float* __restrict__ sinb,
                        const float* __restrict__ qnw,
                        const float* __restrict__ knw,
                        int K)
{
  __shared__ short lA[128 * 32];
  __shared__ short lB[128 * 32];
  const int tid = threadIdx.x;
  const int lane = tid & 63;
  const int wvi = tid >> 6;
  const int l15 = lane & 15, g = lane >> 4;
  const int m0 = blockIdx.x * 128;
  const int nt = blockIdx.y;
  const short* Bp; int n0, region;
  if (MODE == 0) {
    if (nt < 32)      { Bp = B0; n0 = nt * 128;        region = 0; }
    else if (nt < 36) { Bp = B1; n0 = (nt - 32) * 128; region = 1; }
    else              { Bp = B2; n0 = (nt - 36) * 128; region = 2; }
  } else { Bp = B0; n0 = nt * 128; region = 3; }

  const int wrow = wvi * 32;
  const int srow = tid >> 2, schunk = tid & 3;

  f32x4 acc[2][8] = {};

  for (int k0 = 0; k0 < K; k0 += 32) {
    __syncthreads();
#pragma unroll
    for (int c = 0; c < 2; ++c) {
      int row = c * 64 + srow;
      int gc = schunk ^ ((row >> 1) & 3);   // inverse-swizzled global source
      GLDS(A  + (size_t)(m0 + row) * K + k0 + gc * 8, lA + (c * 256 + tid) * 8);
      GLDS(Bp + (size_t)(n0 + row) * K + k0 + gc * 8, lB + (c * 256 + tid) * 8);
    }
    __syncthreads();
    short8 afr[2], bfr[8];
#pragma unroll
    for (int i = 0; i < 2; ++i) {
      int ra = wrow + i * 16 + l15;
      afr[i] = *(const short8*)(lA + ra * 32 + ((g ^ ((ra >> 1) & 3)) * 8));
    }
#pragma unroll
    for (int i = 0; i < 8; ++i) {
      int rb = i * 16 + l15;
      bfr[i] = *(const short8*)(lB + rb * 32 + ((g ^ ((rb >> 1) & 3)) * 8));
    }
#pragma unroll
    for (int mi = 0; mi < 2; ++mi)
#pragma unroll
      for (int ni = 0; ni < 8; ++ni)
        acc[mi][ni] = __builtin_amdgcn_mfma_f32_16x16x32_bf16(afr[mi], bfr[ni], acc[mi][ni], 0, 0, 0);
  }

  // ---- epilogue ----
  if (MODE == 1) {
#pragma unroll
    for (int mi = 0; mi < 2; ++mi)
#pragma unroll
      for (int r = 0; r < 4; ++r) {
        int m = m0 + wrow + mi * 16 + g * 4 + r;
#pragma unroll
        for (int ni = 0; ni < 8; ++ni)
          of[(size_t)m * 2048 + n0 + ni * 16 + l15] = acc[mi][ni][r];
      }
  } else if (region == 2) {
    // v: plain transposed store [b][kv][d][s]
#pragma unroll
    for (int mi = 0; mi < 2; ++mi)
#pragma unroll
      for (int r = 0; r < 4; ++r) {
        int m = m0 + wrow + mi * 16 + g * 4 + r;
        int b = m >> 11, s = m & 2047;
#pragma unroll
        for (int ni = 0; ni < 8; ++ni) {
          int n = n0 + ni * 16 + l15;
          int kvi = n >> 7, d = n & 127;
          ov[(((size_t)b * KVc + kvi) * 128 + d) * Ss + s] = f2bf(acc[mi][ni][r]);
        }
      }
  } else {
    // q / k: fused RMSNorm (over full D=128) + RoPE, all in-lane
    const float* wnorm = (region == 0) ? qnw : knw;
    float w8[8];
#pragma unroll
    for (int ni = 0; ni < 8; ++ni) w8[ni] = wnorm[ni * 16 + l15];
#pragma unroll
    for (int mi = 0; mi < 2; ++mi)
#pragma unroll
      for (int r = 0; r < 4; ++r) {
        int m = m0 + wrow + mi * 16 + g * 4 + r;
        int b = m >> 11, s = m & 2047;
        float xv[8];
        float ssq = 0.f;
#pragma unroll
        for (int ni = 0; ni < 8; ++ni) { xv[ni] = acc[mi][ni][r]; ssq += xv[ni] * xv[ni]; }
        ssq += __shfl_xor(ssq, 1);
        ssq += __shfl_xor(ssq, 2);
        ssq += __shfl_xor(ssq, 4);
        ssq += __shfl_xor(ssq, 8);
        float inv = rsqrtf(ssq * (1.0f / 128.0f) + EPSc);
        float xn[8];
#pragma unroll
        for (int ni = 0; ni < 8; ++ni) xn[ni] = xv[ni] * inv * w8[ni];
        const float* cpr = cosb + ((size_t)b * Ss + s) * Dc;
        const float* spr = sinb + ((size_t)b * Ss + s) * Dc;
#pragma unroll
        for (int ni = 0; ni < 8; ++ni) {
          int dl = ni * 16 + l15;                  // d = n mod 128
          float c = cpr[dl], sn = spr[dl];
          float rot = (ni < 4) ? -xn[ni + 4] : xn[ni - 4];
          float o = xn[ni] * c + rot * sn;
          int n = n0 + dl;
          if (region == 0) {
            oq[(size_t)m * 4096 + n] = f2bf(o * SCALEc);
          } else {
            int kvi = n >> 7, d = n & 127;
            ok[(((size_t)b * KVc + kvi) * Ss + s) * 128 + d] = f2bf(o);
          }
        }
      }
  }
}

// ---------------- Flash attention (GQA, causal) ----------------
// 4 waves x 32 q-rows = 128-row q tile per block. Causal pairing: block pi
// handles q-tiles (pi, 15-pi) sequentially -> every block does 34 k-iters.
// KVBLK=64, double-buffered LDS, counted vmcnt (never drain-0 in loop).
// Swapped QK^T: mfma(A=K, B=Q) -> lane holds S^T[k_local=4g+r][q_local=l15].
// Q comes pre-scaled by 1/sqrt(D). Defer-max (THR=8) skips O-rescale.
__launch_bounds__(256, 2)
__global__ void attn_fwd(const short* __restrict__ qb,
                         const short* __restrict__ kbuf,
                         const short* __restrict__ vtbuf,
                         short* __restrict__ ob)
{
  __shared__ short lK[2][64 * 128];   // 32 KiB
  __shared__ short lV[2][128 * 64];   // 32 KiB
  __shared__ short lP[4][32 * 32];    //  8 KiB
  const int tid = threadIdx.x, lane = tid & 63, wvi = tid >> 6;
  const int l15 = lane & 15, g = lane >> 4;
  const int pi = blockIdx.x, h = blockIdx.y, b = blockIdx.z;
  const int kv = h >> 3;              // G = 8
  const short* kp = kbuf  + ((size_t)b * KVc + kv) * Ss * 128;
  const short* vp = vtbuf + ((size_t)b * KVc + kv) * 128 * Ss;
  const int krow = tid >> 4, kch = tid & 15;   // K tile [64][128]: 16 chunks/row
  const int vrow = tid >> 3, vch = tid & 7;    // V^T tile [128][64]: 8 chunks/row

  for (int which = 0; which < 2; ++which) {
    const int qt = which ? (15 - pi) : pi;
    const int qwb = qt * 128 + wvi * 32;
    const int nkt = 2 * qt + 2;       // 64-key tiles needed

    short8 qf[2][4];
#pragma unroll
    for (int qs = 0; qs < 2; ++qs)
#pragma unroll
      for (int dc = 0; dc < 4; ++dc)
        qf[qs][dc] = *(const short8*)(qb + (size_t)(b * Ss + qwb + qs * 16 + l15) * 4096
                                         + h * 128 + dc * 32 + g * 8);

    f32x4 oacc[2][8] = {};
    float mrun[2] = { -__builtin_inff(), -__builtin_inff() };
    float lrun[2] = { 0.f, 0.f };

    auto STAGE = [&](int kt, int bufi) {   // 8 GLDS per lane
      const int kb0 = kt * 64;
#pragma unroll
      for (int c = 0; c < 4; ++c) {        // K [64][128]
        int r = c * 16 + krow;
        int gc = kch ^ (r & 7);
        GLDS(kp + (size_t)(kb0 + r) * 128 + gc * 8, &lK[bufi][(c * 256 + tid) * 8]);
      }
#pragma unroll
      for (int c = 0; c < 4; ++c) {        // V^T [128][64]
        int r = c * 32 + vrow;
        int gc = vch ^ (r & 7);
        GLDS(vp + (size_t)r * Ss + kb0 + gc * 8, &lV[bufi][(c * 256 + tid) * 8]);
      }
    };

    STAGE(0, 0);
    STAGE(1, 1);                        // nkt >= 2 always

    for (int kt = 0; kt < nkt; ++kt) {
      const int cb = kt & 1;
      if (kt + 1 < nkt) asm volatile("s_waitcnt vmcnt(8)" ::: "memory");
      else              asm volatile("s_waitcnt vmcnt(0)" ::: "memory");
      __builtin_amdgcn_s_barrier();
      asm volatile("" ::: "memory");

#pragma unroll
      for (int half = 0; half < 2; ++half) {
        const int kb0 = kt * 64 + half * 32;
        if (kb0 <= qwb + 31) {
          short8 kf[2][4];
#pragma unroll
          for (int ks = 0; ks < 2; ++ks)
#pragma unroll
            for (int dc = 0; dc < 4; ++dc) {
              int row = half * 32 + ks * 16 + l15;
              kf[ks][dc] = *(const short8*)(&lK[cb][0] + row * 128 + (((dc * 4 + g) ^ (row & 7)) * 8));
            }
          f32x4 st[2][2] = {};
          __builtin_amdgcn_s_setprio(1);
#pragma unroll
          for (int qs = 0; qs < 2; ++qs)
#pragma unroll
            for (int ks = 0; ks < 2; ++ks)
#pragma unroll
              for (int dc = 0; dc < 4; ++dc)
                st[qs][ks] = __builtin_amdgcn_mfma_f32_16x16x32_bf16(kf[ks][dc], qf[qs][dc], st[qs][ks], 0, 0, 0);
          __builtin_amdgcn_s_setprio(0);

          const bool need_mask = (kb0 + 31 > qwb);
#pragma unroll
          for (int qs = 0; qs < 2; ++qs) {
            const int qg = qwb + qs * 16 + l15;
            float p[8];
            float tmax = -__builtin_inff();
#pragma unroll
            for (int ks = 0; ks < 2; ++ks)
#pragma unroll
              for (int r = 0; r < 4; ++r) {
                float v = st[qs][ks][r];
                if (need_mask && (kb0 + ks * 16 + g * 4 + r > qg)) v = -__builtin_inff();
                p[ks * 4 + r] = v;
                tmax = fmaxf(tmax, v);
              }
            tmax = fmaxf(tmax, __shfl_xor(tmax, 16));
            tmax = fmaxf(tmax, __shfl_xor(tmax, 32));
            // defer-max: only rescale O when the running max grows by > 8
            float m_use = mrun[qs];
            if (__any(tmax > m_use + 8.0f)) {
              float mnew = fmaxf(m_use, tmax);
              float scl = __expf(m_use - mnew);   // -inf first tile -> 0
              lrun[qs] *= scl;
              mrun[qs] = mnew;
#pragma unroll
              for (int r = 0; r < 4; ++r) {
                float sc = __shfl(scl, g * 4 + r);
#pragma unroll
                for (int dt = 0; dt < 8; ++dt)
                  oacc[qs][dt][r] *= sc;
              }
              m_use = mnew;
            }
            float rsum = 0.f;
#pragma unroll
            for (int j = 0; j < 8; ++j) { p[j] = __expf(p[j] - m_use); rsum += p[j]; }
            rsum += __shfl_xor(rsum, 16);
            rsum += __shfl_xor(rsum, 32);
            lrun[qs] += rsum;
            {
              int row = qs * 16 + l15;
              int sw = (row >> 1) & 3;
              short* pr = lP[wvi] + row * 32;
#pragma unroll
              for (int ks = 0; ks < 2; ++ks) {
                int idx = (((2 * ks + (g >> 1)) ^ sw) * 8) + (g & 1) * 4; // k = 16ks+4g+r
                short4 pw;
                pw.x = f2bf(p[ks * 4 + 0]);
                pw.y = f2bf(p[ks * 4 + 1]);
                pw.z = f2bf(p[ks * 4 + 2]);
                pw.w = f2bf(p[ks * 4 + 3]);
                *(short4*)(pr + idx) = pw;
              }
            }
          }
          asm volatile("" ::: "memory");   // order lP writes before lP reads (in-wave)
          short8 vf[8];
#pragma unroll
          for (int dt = 0; dt < 8; ++dt) {
            int row = dt * 16 + l15;
            vf[dt] = *(const short8*)(&lV[cb][0] + row * 64 + (((half * 4 + g) ^ (row & 7)) * 8));
          }
          __builtin_amdgcn_s_setprio(1);
#pragma unroll
          for (int qs = 0; qs < 2; ++qs) {
            int row = qs * 16 + l15;
            short8 pf = *(const short8*)(lP[wvi] + row * 32 + ((g ^ ((row >> 1) & 3)) * 8));
#pragma unroll
            for (int dt = 0; dt < 8; ++dt)
              oacc[qs][dt] = __builtin_amdgcn_mfma_f32_16x16x32_bf16(pf, vf[dt], oacc[qs][dt], 0, 0, 0);
          }
          __builtin_amdgcn_s_setprio(0);
          asm volatile("" ::: "memory");
        }
      }

      asm volatile("" ::: "memory");
      __builtin_amdgcn_s_barrier();      // everyone done reading buf[cb]
      if (kt + 2 < nkt) STAGE(kt + 2, cb);
    }

#pragma unroll
    for (int qs = 0; qs < 2; ++qs)
#pragma unroll
      for (int r = 0; r < 4; ++r) {
        float inv = 1.0f / __shfl(lrun[qs], g * 4 + r);
        int qrow = qwb + qs * 16 + g * 4 + r;
        short* op = ob + (size_t)(b * Ss + qrow) * 4096 + h * 128;
#pragma unroll
        for (int dt = 0; dt < 8; ++dt)
          op[dt * 16 + l15] = f2bf(oacc[qs][dt][r] * inv);
      }
  }
}

// ---------------- host ----------------
extern "C" void kernel_launch(void* const* d_in, const int* in_sizes, int n_in,
                              void* d_out, int out_size, void* d_ws, size_t ws_size,
                              hipStream_t stream) {
  const float* x    = (const float*)d_in[0];
  const float* cosb = (const float*)d_in[1];
  const float* sinb = (const float*)d_in[2];
  const float* wq   = (const float*)d_in[3];
  const float* wk   = (const float*)d_in[4];
  const float* wv   = (const float*)d_in[5];
  const float* wo   = (const float*)d_in[6];
  const float* qw   = (const float*)d_in[7];
  const float* kw   = (const float*)d_in[8];

  size_t off = 0;
  auto alloc = [&](size_t bytes) {
    char* p = (char*)d_ws + off;
    off += (bytes + 255) & ~(size_t)255;
    return p;
  };
  short* x_bf  = (short*)alloc((size_t)8388608 * 2);
  short* wq_bf = (short*)alloc((size_t)8388608 * 2);
  short* wk_bf = (short*)alloc((size_t)1048576 * 2);
  short* wv_bf = (short*)alloc((size_t)1048576 * 2);
  short* wo_bf = (short*)alloc((size_t)8388608 * 2);
  short* q_bf  = (short*)alloc((size_t)16777216 * 2);
  short* k_bf  = (short*)alloc((size_t)2097152 * 2);
  short* v_bf  = (short*)alloc((size_t)2097152 * 2);
  short* ao_bf = (short*)alloc((size_t)16777216 * 2);

  Cvt5 ca;
  ca.src[0] = x;    ca.dst[0] = x_bf;
  ca.src[1] = wq;   ca.dst[1] = wq_bf;
  ca.src[2] = wk;   ca.dst[2] = wk_bf;
  ca.src[3] = wv;   ca.dst[3] = wv_bf;
  ca.src[4] = wo;   ca.dst[4] = wo_bf;
  cvt_all<<<2048, 256, 0, stream>>>(ca);

  gemm_bt<0><<<dim3(32, 40), 256, 0, stream>>>(x_bf, wq_bf, wk_bf, wv_bf,
                                               q_bf, k_bf, v_bf, nullptr,
                                               cosb, sinb, qw, kw, 2048);
  attn_fwd<<<dim3(8, 32, 2), 256, 0, stream>>>(q_bf, k_bf, v_bf, ao_bf);
  gemm_bt<1><<<dim3(32, 16), 256, 0, stream>>>(ao_bf, wo_bf, nullptr, nullptr,
                                               nullptr, nullptr, nullptr, (float*)d_out,
                                               nullptr, nullptr, nullptr, nullptr, 4096);
}

// Round 5
// 353.439 us; speedup vs baseline: 1.0900x; 1.0044x over previous
//
#include <hip/hip_runtime.h>
#include <hip/hip_bf16.h>

typedef __attribute__((ext_vector_type(8))) short short8;
typedef __attribute__((ext_vector_type(4))) float f32x4;

#define DEVI static __device__ __forceinline__

constexpr int Bb = 2, Ss = 2048, Hh = 32, KVc = 4, Dc = 128;
constexpr float EPSc = 1e-6f;
constexpr float SCALEc = 0.08838834764831845f; // 1/sqrt(128)

DEVI float bf2f(short s) {
  unsigned u = ((unsigned)(unsigned short)s) << 16;
  float f; __builtin_memcpy(&f, &u, 4); return f;
}
DEVI short f2bf(float f) {
  __hip_bfloat16 h = __float2bfloat16(f);
  unsigned short u; __builtin_memcpy(&u, &h, 2); return (short)u;
}

// async global->LDS, 16B per lane. LDS dest must be linear (base + lane*16).
#define GLDS(gsrc, ldst) __builtin_amdgcn_global_load_lds( \
    (const __attribute__((address_space(1))) void*)(gsrc), \
    (__attribute__((address_space(3))) void*)(ldst), 16, 0, 0)

// ---------------- fused f32 -> bf16 convert (5 segments, 1 launch) ----------------
struct Cvt5 { const float* src[5]; short* dst[5]; };
__global__ void cvt_all(Cvt5 a) {
  // float4 counts: x 2097152, wq 2097152, wk 262144, wv 262144, wo 2097152
  constexpr int CUM[6] = {0, 2097152, 4194304, 4456448, 4718592, 6815744};
  const int stride = gridDim.x * blockDim.x;
  for (int i = blockIdx.x * blockDim.x + threadIdx.x; i < 6815744; i += stride) {
    int s = 0;
#pragma unroll
    for (int t = 1; t < 5; ++t) if (i >= CUM[t]) s = t;
    int j = i - CUM[s];
    float4 v = ((const float4*)a.src[s])[j];
    short4 o;
    o.x = f2bf(v.x); o.y = f2bf(v.y); o.z = f2bf(v.z); o.w = f2bf(v.w);
    ((short4*)a.dst[s])[j] = o;
  }
}

// ---------------- GEMM: C[m][n] = sum_k A[m][k] * B[n][k]  (both row-major, bf16) ----
// Grid dim3(32, nt): bid%8 == m_tile%8 -> A-tiles are XCD-stationary in L2.
// Double-buffered LDS + raw s_barrier + counted vmcnt(4) (prefetch distance 2,
// never drain-0 in the main loop) -- same schedule as attn_fwd's K-loop.
// Wave tile 32m x 128n: each wave owns full head-dim per row -> RMSNorm+RoPE
// fuse entirely in-lane (partner col n^64 is ni^4 in the same lane).
// MODE 0: fused QKV. q: norm+rope+scale; k: norm+rope -> [b][kv][s][d]; v -> [b][kv][d][s].
// MODE 1: out-proj, f32 row-major out (N=2048).
template<int MODE>
__launch_bounds__(256, 4)
__global__ void gemm_bt(const short* __restrict__ A,
                        const short* __restrict__ B0,
                        const short* __restrict__ B1,
                        const short* __restrict__ B2,
                        short* __restrict__ oq,
                        short* __restrict__ ok,
                        short* __restrict__ ov,
                        float* __restrict__ of,
                        const float* __restrict__ cosb,
                        const float* __restrict__ sinb,
                        const float* __restrict__ qnw,
                        const float* __restrict__ knw,
                        int K)
{
  __shared__ short lA[2][128 * 32];
  __shared__ short lB[2][128 * 32];
  const int tid = threadIdx.x;
  const int lane = tid & 63;
  const int wvi = tid >> 6;
  const int l15 = lane & 15, g = lane >> 4;
  const int m0 = blockIdx.x * 128;
  const int nt = blockIdx.y;
  const short* Bp; int n0, region;
  if (MODE == 0) {
    if (nt < 32)      { Bp = B0; n0 = nt * 128;        region = 0; }
    else if (nt < 36) { Bp = B1; n0 = (nt - 32) * 128; region = 1; }
    else              { Bp = B2; n0 = (nt - 36) * 128; region = 2; }
  } else { Bp = B0; n0 = nt * 128; region = 3; }

  const int wrow = wvi * 32;
  const int srow = tid >> 2, schunk = tid & 3;

  f32x4 acc[2][8] = {};

  auto STAGE = [&](int ks, int bufi) {   // 4 GLDS per lane
    const int k0 = ks * 32;
#pragma unroll
    for (int c = 0; c < 2; ++c) {
      int row = c * 64 + srow;
      int gc = schunk ^ ((row >> 1) & 3);   // inverse-swizzled global source
      GLDS(A  + (size_t)(m0 + row) * K + k0 + gc * 8, &lA[bufi][(c * 256 + tid) * 8]);
      GLDS(Bp + (size_t)(n0 + row) * K + k0 + gc * 8, &lB[bufi][(c * 256 + tid) * 8]);
    }
  };

  const int nks = K >> 5;
  STAGE(0, 0);
  STAGE(1, 1);

  for (int ks = 0; ks < nks; ++ks) {
    const int cb = ks & 1;
    if (ks + 1 < nks) asm volatile("s_waitcnt vmcnt(4)" ::: "memory");
    else              asm volatile("s_waitcnt vmcnt(0)" ::: "memory");
    __builtin_amdgcn_s_barrier();
    asm volatile("" ::: "memory");

    short8 afr[2], bfr[8];
#pragma unroll
    for (int i = 0; i < 2; ++i) {
      int ra = wrow + i * 16 + l15;
      afr[i] = *(const short8*)(&lA[cb][0] + ra * 32 + ((g ^ ((ra >> 1) & 3)) * 8));
    }
#pragma unroll
    for (int i = 0; i < 8; ++i) {
      int rb = i * 16 + l15;
      bfr[i] = *(const short8*)(&lB[cb][0] + rb * 32 + ((g ^ ((rb >> 1) & 3)) * 8));
    }
#pragma unroll
    for (int mi = 0; mi < 2; ++mi)
#pragma unroll
      for (int ni = 0; ni < 8; ++ni)
        acc[mi][ni] = __builtin_amdgcn_mfma_f32_16x16x32_bf16(afr[mi], bfr[ni], acc[mi][ni], 0, 0, 0);

    asm volatile("" ::: "memory");
    __builtin_amdgcn_s_barrier();        // all waves done reading buf[cb]
    if (ks + 2 < nks) STAGE(ks + 2, cb);
  }

  // ---- epilogue ----
  if (MODE == 1) {
#pragma unroll
    for (int mi = 0; mi < 2; ++mi)
#pragma unroll
      for (int r = 0; r < 4; ++r) {
        int m = m0 + wrow + mi * 16 + g * 4 + r;
#pragma unroll
        for (int ni = 0; ni < 8; ++ni)
          of[(size_t)m * 2048 + n0 + ni * 16 + l15] = acc[mi][ni][r];
      }
  } else if (region == 2) {
    // v: plain transposed store [b][kv][d][s]
#pragma unroll
    for (int mi = 0; mi < 2; ++mi)
#pragma unroll
      for (int r = 0; r < 4; ++r) {
        int m = m0 + wrow + mi * 16 + g * 4 + r;
        int b = m >> 11, s = m & 2047;
#pragma unroll
        for (int ni = 0; ni < 8; ++ni) {
          int n = n0 + ni * 16 + l15;
          int kvi = n >> 7, d = n & 127;
          ov[(((size_t)b * KVc + kvi) * 128 + d) * Ss + s] = f2bf(acc[mi][ni][r]);
        }
      }
  } else {
    // q / k: fused RMSNorm (over full D=128) + RoPE, all in-lane
    const float* wnorm = (region == 0) ? qnw : knw;
    float w8[8];
#pragma unroll
    for (int ni = 0; ni < 8; ++ni) w8[ni] = wnorm[ni * 16 + l15];
#pragma unroll
    for (int mi = 0; mi < 2; ++mi)
#pragma unroll
      for (int r = 0; r < 4; ++r) {
        int m = m0 + wrow + mi * 16 + g * 4 + r;
        int b = m >> 11, s = m & 2047;
        float xv[8];
        float ssq = 0.f;
#pragma unroll
        for (int ni = 0; ni < 8; ++ni) { xv[ni] = acc[mi][ni][r]; ssq += xv[ni] * xv[ni]; }
        ssq += __shfl_xor(ssq, 1);
        ssq += __shfl_xor(ssq, 2);
        ssq += __shfl_xor(ssq, 4);
        ssq += __shfl_xor(ssq, 8);
        float inv = rsqrtf(ssq * (1.0f / 128.0f) + EPSc);
        float xn[8];
#pragma unroll
        for (int ni = 0; ni < 8; ++ni) xn[ni] = xv[ni] * inv * w8[ni];
        const float* cpr = cosb + ((size_t)b * Ss + s) * Dc;
        const float* spr = sinb + ((size_t)b * Ss + s) * Dc;
#pragma unroll
        for (int ni = 0; ni < 8; ++ni) {
          int dl = ni * 16 + l15;                  // d = n mod 128
          float c = cpr[dl], sn = spr[dl];
          float rot = (ni < 4) ? -xn[ni + 4] : xn[ni - 4];
          float o = xn[ni] * c + rot * sn;
          int n = n0 + dl;
          if (region == 0) {
            oq[(size_t)m * 4096 + n] = f2bf(o * SCALEc);
          } else {
            int kvi = n >> 7, d = n & 127;
            ok[(((size_t)b * KVc + kvi) * Ss + s) * 128 + d] = f2bf(o);
          }
        }
      }
  }
}

// ---------------- Flash attention (GQA, causal) ----------------
// 4 waves x 32 q-rows = 128-row q tile per block. Causal pairing: block pi
// handles q-tiles (pi, 15-pi) sequentially -> every block does 34 k-iters.
// KVBLK=64, double-buffered LDS, counted vmcnt (never drain-0 in loop).
// Swapped QK^T: mfma(A=K, B=Q) -> lane holds S^T[k_local=4g+r][q_local=l15].
// Q comes pre-scaled by 1/sqrt(D). Defer-max (THR=8) skips O-rescale.
__launch_bounds__(256, 2)
__global__ void attn_fwd(const short* __restrict__ qb,
                         const short* __restrict__ kbuf,
                         const short* __restrict__ vtbuf,
                         short* __restrict__ ob)
{
  __shared__ short lK[2][64 * 128];   // 32 KiB
  __shared__ short lV[2][128 * 64];   // 32 KiB
  __shared__ short lP[4][32 * 32];    //  8 KiB
  const int tid = threadIdx.x, lane = tid & 63, wvi = tid >> 6;
  const int l15 = lane & 15, g = lane >> 4;
  const int pi = blockIdx.x, h = blockIdx.y, b = blockIdx.z;
  const int kv = h >> 3;              // G = 8
  const short* kp = kbuf  + ((size_t)b * KVc + kv) * Ss * 128;
  const short* vp = vtbuf + ((size_t)b * KVc + kv) * 128 * Ss;
  const int krow = tid >> 4, kch = tid & 15;   // K tile [64][128]: 16 chunks/row
  const int vrow = tid >> 3, vch = tid & 7;    // V^T tile [128][64]: 8 chunks/row

  for (int which = 0; which < 2; ++which) {
    const int qt = which ? (15 - pi) : pi;
    const int qwb = qt * 128 + wvi * 32;
    const int nkt = 2 * qt + 2;       // 64-key tiles needed

    short8 qf[2][4];
#pragma unroll
    for (int qs = 0; qs < 2; ++qs)
#pragma unroll
      for (int dc = 0; dc < 4; ++dc)
        qf[qs][dc] = *(const short8*)(qb + (size_t)(b * Ss + qwb + qs * 16 + l15) * 4096
                                         + h * 128 + dc * 32 + g * 8);

    f32x4 oacc[2][8] = {};
    float mrun[2] = { -__builtin_inff(), -__builtin_inff() };
    float lrun[2] = { 0.f, 0.f };

    auto STAGE = [&](int kt, int bufi) {   // 8 GLDS per lane
      const int kb0 = kt * 64;
#pragma unroll
      for (int c = 0; c < 4; ++c) {        // K [64][128]
        int r = c * 16 + krow;
        int gc = kch ^ (r & 7);
        GLDS(kp + (size_t)(kb0 + r) * 128 + gc * 8, &lK[bufi][(c * 256 + tid) * 8]);
      }
#pragma unroll
      for (int c = 0; c < 4; ++c) {        // V^T [128][64]
        int r = c * 32 + vrow;
        int gc = vch ^ (r & 7);
        GLDS(vp + (size_t)r * Ss + kb0 + gc * 8, &lV[bufi][(c * 256 + tid) * 8]);
      }
    };

    STAGE(0, 0);
    STAGE(1, 1);                        // nkt >= 2 always

    for (int kt = 0; kt < nkt; ++kt) {
      const int cb = kt & 1;
      if (kt + 1 < nkt) asm volatile("s_waitcnt vmcnt(8)" ::: "memory");
      else              asm volatile("s_waitcnt vmcnt(0)" ::: "memory");
      __builtin_amdgcn_s_barrier();
      asm volatile("" ::: "memory");

#pragma unroll
      for (int half = 0; half < 2; ++half) {
        const int kb0 = kt * 64 + half * 32;
        if (kb0 <= qwb + 31) {
          short8 kf[2][4];
#pragma unroll
          for (int ks = 0; ks < 2; ++ks)
#pragma unroll
            for (int dc = 0; dc < 4; ++dc) {
              int row = half * 32 + ks * 16 + l15;
              kf[ks][dc] = *(const short8*)(&lK[cb][0] + row * 128 + (((dc * 4 + g) ^ (row & 7)) * 8));
            }
          f32x4 st[2][2] = {};
          __builtin_amdgcn_s_setprio(1);
#pragma unroll
          for (int qs = 0; qs < 2; ++qs)
#pragma unroll
            for (int ks = 0; ks < 2; ++ks)
#pragma unroll
              for (int dc = 0; dc < 4; ++dc)
                st[qs][ks] = __builtin_amdgcn_mfma_f32_16x16x32_bf16(kf[ks][dc], qf[qs][dc], st[qs][ks], 0, 0, 0);
          __builtin_amdgcn_s_setprio(0);

          const bool need_mask = (kb0 + 31 > qwb);
#pragma unroll
          for (int qs = 0; qs < 2; ++qs) {
            const int qg = qwb + qs * 16 + l15;
            float p[8];
            float tmax = -__builtin_inff();
#pragma unroll
            for (int ks = 0; ks < 2; ++ks)
#pragma unroll
              for (int r = 0; r < 4; ++r) {
                float v = st[qs][ks][r];
                if (need_mask && (kb0 + ks * 16 + g * 4 + r > qg)) v = -__builtin_inff();
                p[ks * 4 + r] = v;
                tmax = fmaxf(tmax, v);
              }
            tmax = fmaxf(tmax, __shfl_xor(tmax, 16));
            tmax = fmaxf(tmax, __shfl_xor(tmax, 32));
            // defer-max: only rescale O when the running max grows by > 8
            float m_use = mrun[qs];
            if (__any(tmax > m_use + 8.0f)) {
              float mnew = fmaxf(m_use, tmax);
              float scl = __expf(m_use - mnew);   // -inf first tile -> 0
              lrun[qs] *= scl;
              mrun[qs] = mnew;
#pragma unroll
              for (int r = 0; r < 4; ++r) {
                float sc = __shfl(scl, g * 4 + r);
#pragma unroll
                for (int dt = 0; dt < 8; ++dt)
                  oacc[qs][dt][r] *= sc;
              }
              m_use = mnew;
            }
            float rsum = 0.f;
#pragma unroll
            for (int j = 0; j < 8; ++j) { p[j] = __expf(p[j] - m_use); rsum += p[j]; }
            rsum += __shfl_xor(rsum, 16);
            rsum += __shfl_xor(rsum, 32);
            lrun[qs] += rsum;
            {
              int row = qs * 16 + l15;
              int sw = (row >> 1) & 3;
              short* pr = lP[wvi] + row * 32;
#pragma unroll
              for (int ks = 0; ks < 2; ++ks) {
                int idx = (((2 * ks + (g >> 1)) ^ sw) * 8) + (g & 1) * 4; // k = 16ks+4g+r
                short4 pw;
                pw.x = f2bf(p[ks * 4 + 0]);
                pw.y = f2bf(p[ks * 4 + 1]);
                pw.z = f2bf(p[ks * 4 + 2]);
                pw.w = f2bf(p[ks * 4 + 3]);
                *(short4*)(pr + idx) = pw;
              }
            }
          }
          asm volatile("" ::: "memory");   // order lP writes before lP reads (in-wave)
          short8 vf[8];
#pragma unroll
          for (int dt = 0; dt < 8; ++dt) {
            int row = dt * 16 + l15;
            vf[dt] = *(const short8*)(&lV[cb][0] + row * 64 + (((half * 4 + g) ^ (row & 7)) * 8));
          }
          __builtin_amdgcn_s_setprio(1);
#pragma unroll
          for (int qs = 0; qs < 2; ++qs) {
            int row = qs * 16 + l15;
            short8 pf = *(const short8*)(lP[wvi] + row * 32 + ((g ^ ((row >> 1) & 3)) * 8));
#pragma unroll
            for (int dt = 0; dt < 8; ++dt)
              oacc[qs][dt] = __builtin_amdgcn_mfma_f32_16x16x32_bf16(pf, vf[dt], oacc[qs][dt], 0, 0, 0);
          }
          __builtin_amdgcn_s_setprio(0);
          asm volatile("" ::: "memory");
        }
      }

      asm volatile("" ::: "memory");
      __builtin_amdgcn_s_barrier();      // everyone done reading buf[cb]
      if (kt + 2 < nkt) STAGE(kt + 2, cb);
    }

#pragma unroll
    for (int qs = 0; qs < 2; ++qs)
#pragma unroll
      for (int r = 0; r < 4; ++r) {
        float inv = 1.0f / __shfl(lrun[qs], g * 4 + r);
        int qrow = qwb + qs * 16 + g * 4 + r;
        short* op = ob + (size_t)(b * Ss + qrow) * 4096 + h * 128;
#pragma unroll
        for (int dt = 0; dt < 8; ++dt)
          op[dt * 16 + l15] = f2bf(oacc[qs][dt][r] * inv);
      }
  }
}

// ---------------- host ----------------
extern "C" void kernel_launch(void* const* d_in, const int* in_sizes, int n_in,
                              void* d_out, int out_size, void* d_ws, size_t ws_size,
                              hipStream_t stream) {
  const float* x    = (const float*)d_in[0];
  const float* cosb = (const float*)d_in[1];
  const float* sinb = (const float*)d_in[2];
  const float* wq   = (const float*)d_in[3];
  const float* wk   = (const float*)d_in[4];
  const float* wv   = (const float*)d_in[5];
  const float* wo   = (const float*)d_in[6];
  const float* qw   = (const float*)d_in[7];
  const float* kw   = (const float*)d_in[8];

  size_t off = 0;
  auto alloc = [&](size_t bytes) {
    char* p = (char*)d_ws + off;
    off += (bytes + 255) & ~(size_t)255;
    return p;
  };
  short* x_bf  = (short*)alloc((size_t)8388608 * 2);
  short* wq_bf = (short*)alloc((size_t)8388608 * 2);
  short* wk_bf = (short*)alloc((size_t)1048576 * 2);
  short* wv_bf = (short*)alloc((size_t)1048576 * 2);
  short* wo_bf = (short*)alloc((size_t)8388608 * 2);
  short* q_bf  = (short*)alloc((size_t)16777216 * 2);
  short* k_bf  = (short*)alloc((size_t)2097152 * 2);
  short* v_bf  = (short*)alloc((size_t)2097152 * 2);
  short* ao_bf = (short*)alloc((size_t)16777216 * 2);

  Cvt5 ca;
  ca.src[0] = x;    ca.dst[0] = x_bf;
  ca.src[1] = wq;   ca.dst[1] = wq_bf;
  ca.src[2] = wk;   ca.dst[2] = wk_bf;
  ca.src[3] = wv;   ca.dst[3] = wv_bf;
  ca.src[4] = wo;   ca.dst[4] = wo_bf;
  cvt_all<<<2048, 256, 0, stream>>>(ca);

  gemm_bt<0><<<dim3(32, 40), 256, 0, stream>>>(x_bf, wq_bf, wk_bf, wv_bf,
                                               q_bf, k_bf, v_bf, nullptr,
                                               cosb, sinb, qw, kw, 2048);
  attn_fwd<<<dim3(8, 32, 2), 256, 0, stream>>>(q_bf, k_bf, v_bf, ao_bf);
  gemm_bt<1><<<dim3(32, 16), 256, 0, stream>>>(ao_bf, wo_bf, nullptr, nullptr,
                                               nullptr, nullptr, nullptr, (float*)d_out,
                                               nullptr, nullptr, nullptr, nullptr, 4096);
}